// Round 3
// baseline (3212.923 us; speedup 1.0000x reference)
//
#include <hip/hip_runtime.h>
#include <hip/hip_bf16.h>

#define HID 64
#define NBATCH 2048
#define NT  512
#define DIN 7
#define SPB 16      // samples per wave/block
#define CTC 16      // time steps staged in LDS per chunk

typedef _Float16 half4 __attribute__((ext_vector_type(4)));
typedef _Float16 half8 __attribute__((ext_vector_type(8)));
typedef float    f32x4 __attribute__((ext_vector_type(4)));

__device__ __forceinline__ float sigm(float x) {
  return __fdividef(1.0f, 1.0f + __expf(-x));   // inf-safe: exp->inf => 0
}
__device__ __forceinline__ float tanh_fast(float v) {
  // tanh(v) = 1 - 2/(1+e^{2v}); inf-safe at both ends, no clamp needed
  return fmaf(-2.0f, __fdividef(1.0f, 1.0f + __expf(2.0f * v)), 1.0f);
}

#define MFMA16(A, B, C) __builtin_amdgcn_mfma_f32_16x16x16f16((A), (B), (C), 0, 0, 0)

// One wave (64 threads) per block owns 16 samples for all 512 steps of both
// GRU layers. Operand-swapped MFMA (D = W·h^T) makes gate-math output land
// exactly in the next step's B-fragment slots: zero barriers, zero cross-lane
// traffic in the recurrence. h kept as f16 hi+lo pair (~fp32 precision, K=128).
__global__ __launch_bounds__(64, 1) void gru_wave(
    const float* __restrict__ x,     // [B][T][7]
    const float* __restrict__ Wih0,  // [192][7]
    const float* __restrict__ Whh0,  // [192][64]
    const float* __restrict__ bih0,  // [192]
    const float* __restrict__ bhh0,  // [192]
    const float* __restrict__ Wih1,  // [192][64]
    const float* __restrict__ Whh1,  // [192][64]
    const float* __restrict__ bih1,  // [192]
    const float* __restrict__ bhh1,  // [192]
    const float* __restrict__ fcW,   // [64]
    const float* __restrict__ fcb,   // [1]
    float* __restrict__ out)         // [2048]
{
  // [mat(ih1,hh1)][ktpair][tile(12)][lane(64)][8 f16] = 48 KiB
  __shared__ __align__(16) _Float16 WL[2 * 2 * 12 * 64 * 8];
  // [t(16)][sample(16)][16 f16 (K slots, 7 real)] = 8 KiB
  __shared__ __align__(16) _Float16 xbuf[CTC * 16 * 16];
  // per layer 256 floats: [0:128)=bih+bhh (r,z), [128:192)=bih_n, [192:256)=bhh_n
  __shared__ __align__(16) float biasLds[2 * 256];

  const int tid = threadIdx.x;
  const int col = tid & 15;   // fragment row/col position
  const int q   = tid >> 4;   // k-quad
  const int s0  = blockIdx.x * SPB;

  // ---- stage biases ----
  for (int g = tid; g < 128; g += 64) {
    biasLds[g]       = bih0[g] + bhh0[g];
    biasLds[256 + g] = bih1[g] + bhh1[g];
  }
  {
    int u = tid;  // 64 threads, 64 values
    biasLds[128 + u]       = bih0[128 + u];
    biasLds[192 + u]       = bhh0[128 + u];
    biasLds[256 + 128 + u] = bih1[128 + u];
    biasLds[256 + 192 + u] = bhh1[128 + u];
  }

  // ---- stage Wih1/Whh1 fragments into LDS (pre-swizzled, 16B/lane slots) ----
  // frag element: W[g=16t+col][k = 16*(2p+kp)+4q+i], kp in {0,1} packed in half8
  for (int mt = 0; mt < 24; ++mt) {
    const float* Wsrc = (mt < 12) ? Wih1 : Whh1;
    const int t = (mt < 12) ? mt : mt - 12;
    const int g = t * 16 + col;
#pragma unroll
    for (int p = 0; p < 2; ++p) {
      f32x4 a = *(const f32x4*)&Wsrc[g * HID + 32 * p + 4 * q];
      f32x4 b = *(const f32x4*)&Wsrc[g * HID + 32 * p + 16 + 4 * q];
      half8 w;
#pragma unroll
      for (int i = 0; i < 4; ++i) { w[i] = (_Float16)a[i]; w[4 + i] = (_Float16)b[i]; }
      *(half8*)&WL[((((mt < 12) ? 0 : 1) * 2 + p) * 12 + t) * 512 + tid * 8] = w;
    }
  }

  // ---- zero xbuf (K slots 7..15 must stay zero) ----
  for (int i = tid; i < CTC * 16 * 16 / 8; i += 64) ((half8*)xbuf)[i] = (half8){};

  // ---- Whh0 / Wih0 fragments into registers ----
  half4 whh0r[12][4], wih0r[12];
#pragma unroll
  for (int t = 0; t < 12; ++t) {
    const int g = t * 16 + col;
#pragma unroll
    for (int kt = 0; kt < 4; ++kt) {
      f32x4 a = *(const f32x4*)&Whh0[g * HID + kt * 16 + 4 * q];
      half4 w;
#pragma unroll
      for (int i = 0; i < 4; ++i) w[i] = (_Float16)a[i];
      whh0r[t][kt] = w;
    }
    half4 w0 = (half4){};
#pragma unroll
    for (int i = 0; i < 4; ++i) {
      const int k = 4 * q + i;
      if (k < DIN) w0[i] = (_Float16)Wih0[g * DIN + k];
    }
    wih0r[t] = w0;
  }

  __syncthreads();

  half4 h0hi[4] = {}, h0lo[4] = {}, h1hi[4] = {}, h1lo[4] = {};

  for (int tc = 0; tc < NT / CTC; ++tc) {
    // ---- stage x chunk: 16 steps x 16 samples x 7 f32 -> f16 frags ----
#pragma unroll
    for (int u = 0; u < 4; ++u) {
      const int idx = u * 64 + tid;
      const int s = idx & 15, tt = idx >> 4;
      const float* xp = x + ((size_t)(s0 + s) * NT + tc * CTC + tt) * DIN;
      half4 lo4 = { (_Float16)xp[0], (_Float16)xp[1], (_Float16)xp[2], (_Float16)xp[3] };
      half4 hi4 = { (_Float16)xp[4], (_Float16)xp[5], (_Float16)xp[6], (_Float16)0.0f };
      *(half4*)&xbuf[(tt * 16 + s) * 16 + 0] = lo4;
      *(half4*)&xbuf[(tt * 16 + s) * 16 + 4] = hi4;
    }
    __syncthreads();

    for (int ti = 0; ti < CTC; ++ti) {
      // x B-fragment: x[sample col][k=4q+i] (zeros for k>=7)
      half4 xb = *(const half4*)&xbuf[(ti * 16 + col) * 16 + q * 4];

      // ======== Layer 0 ========
      f32x4 acc[12], hna[4];
#pragma unroll
      for (int t = 0; t < 12; ++t) {
        f32x4 c = *(const f32x4*)&biasLds[t * 16 + 4 * q];
        acc[t] = MFMA16(wih0r[t], xb, c);
      }
#pragma unroll
      for (int kt = 0; kt < 4; ++kt)
        hna[kt] = *(const f32x4*)&biasLds[192 + kt * 16 + 4 * q];
#pragma unroll
      for (int kk = 0; kk < 4; ++kk) {
#pragma unroll
        for (int t = 0; t < 8; ++t)  acc[t]     = MFMA16(whh0r[t][kk], h0hi[kk], acc[t]);
#pragma unroll
        for (int t = 8; t < 12; ++t) hna[t - 8] = MFMA16(whh0r[t][kk], h0hi[kk], hna[t - 8]);
      }
#pragma unroll
      for (int kk = 0; kk < 4; ++kk) {
#pragma unroll
        for (int t = 0; t < 8; ++t)  acc[t]     = MFMA16(whh0r[t][kk], h0lo[kk], acc[t]);
#pragma unroll
        for (int t = 8; t < 12; ++t) hna[t - 8] = MFMA16(whh0r[t][kk], h0lo[kk], hna[t - 8]);
      }
      // layer0 gate math -> new h0 fragments (in-register, zero cross-lane)
#pragma unroll
      for (int kt = 0; kt < 4; ++kt) {
        half4 nh, nl;
#pragma unroll
        for (int ir = 0; ir < 4; ++ir) {
          const float r = sigm(acc[kt][ir]);
          const float z = sigm(acc[4 + kt][ir]);
          const float n = tanh_fast(fmaf(r, hna[kt][ir], acc[8 + kt][ir]));
          const float hp = (float)h0hi[kt][ir] + (float)h0lo[kt][ir];
          const float h  = fmaf(z, hp - n, n);
          const _Float16 hi = (_Float16)h;
          nh[ir] = hi;
          nl[ir] = (_Float16)(h - (float)hi);
        }
        h0hi[kt] = nh; h0lo[kt] = nl;
      }

      // ======== Layer 1 ========
#pragma unroll
      for (int t = 0; t < 12; ++t) {
        half8 wiA = *(const half8*)&WL[((0 * 2 + 0) * 12 + t) * 512 + tid * 8];
        half8 wiB = *(const half8*)&WL[((0 * 2 + 1) * 12 + t) * 512 + tid * 8];
        half8 whA = *(const half8*)&WL[((1 * 2 + 0) * 12 + t) * 512 + tid * 8];
        half8 whB = *(const half8*)&WL[((1 * 2 + 1) * 12 + t) * 512 + tid * 8];
        half4 wi[4] = { __builtin_shufflevector(wiA, wiA, 0, 1, 2, 3),
                        __builtin_shufflevector(wiA, wiA, 4, 5, 6, 7),
                        __builtin_shufflevector(wiB, wiB, 0, 1, 2, 3),
                        __builtin_shufflevector(wiB, wiB, 4, 5, 6, 7) };
        half4 wh[4] = { __builtin_shufflevector(whA, whA, 0, 1, 2, 3),
                        __builtin_shufflevector(whA, whA, 4, 5, 6, 7),
                        __builtin_shufflevector(whB, whB, 0, 1, 2, 3),
                        __builtin_shufflevector(whB, whB, 4, 5, 6, 7) };
        f32x4 a = *(const f32x4*)&biasLds[256 + t * 16 + 4 * q];
        if (t < 8) {
#pragma unroll
          for (int kk = 0; kk < 4; ++kk) a = MFMA16(wi[kk], h0hi[kk], a);
#pragma unroll
          for (int kk = 0; kk < 4; ++kk) a = MFMA16(wi[kk], h0lo[kk], a);
#pragma unroll
          for (int kk = 0; kk < 4; ++kk) a = MFMA16(wh[kk], h1hi[kk], a);
#pragma unroll
          for (int kk = 0; kk < 4; ++kk) a = MFMA16(wh[kk], h1lo[kk], a);
          acc[t] = a;
        } else {
#pragma unroll
          for (int kk = 0; kk < 4; ++kk) a = MFMA16(wi[kk], h0hi[kk], a);
#pragma unroll
          for (int kk = 0; kk < 4; ++kk) a = MFMA16(wi[kk], h0lo[kk], a);
          acc[t] = a;
          f32x4 b = *(const f32x4*)&biasLds[256 + 192 + (t - 8) * 16 + 4 * q];
#pragma unroll
          for (int kk = 0; kk < 4; ++kk) b = MFMA16(wh[kk], h1hi[kk], b);
#pragma unroll
          for (int kk = 0; kk < 4; ++kk) b = MFMA16(wh[kk], h1lo[kk], b);
          hna[t - 8] = b;
        }
      }
      // layer1 gate math -> new h1 fragments
#pragma unroll
      for (int kt = 0; kt < 4; ++kt) {
        half4 nh, nl;
#pragma unroll
        for (int ir = 0; ir < 4; ++ir) {
          const float r = sigm(acc[kt][ir]);
          const float z = sigm(acc[4 + kt][ir]);
          const float n = tanh_fast(fmaf(r, hna[kt][ir], acc[8 + kt][ir]));
          const float hp = (float)h1hi[kt][ir] + (float)h1lo[kt][ir];
          const float h  = fmaf(z, hp - n, n);
          const _Float16 hi = (_Float16)h;
          nh[ir] = hi;
          nl[ir] = (_Float16)(h - (float)hi);
        }
        h1hi[kt] = nh; h1lo[kt] = nl;
      }
    }
    __syncthreads();
  }

  // ======== epilogue: out[s] = fcW · h1[s] + fcb ========
  float partial = 0.0f;
#pragma unroll
  for (int kt = 0; kt < 4; ++kt)
#pragma unroll
    for (int ir = 0; ir < 4; ++ir)
      partial += ((float)h1hi[kt][ir] + (float)h1lo[kt][ir]) * fcW[kt * 16 + 4 * q + ir];
  partial += __shfl_xor(partial, 16, 64);
  partial += __shfl_xor(partial, 32, 64);
  if (tid < 16) out[s0 + tid] = partial + fcb[0];
}

extern "C" void kernel_launch(void* const* d_in, const int* in_sizes, int n_in,
                              void* d_out, int out_size, void* d_ws, size_t ws_size,
                              hipStream_t stream) {
  (void)in_sizes; (void)n_in; (void)d_ws; (void)ws_size; (void)out_size;
  gru_wave<<<NBATCH / SPB, 64, 0, stream>>>(
      (const float*)d_in[0],  (const float*)d_in[1],
      (const float*)d_in[2],  (const float*)d_in[3],
      (const float*)d_in[4],  (const float*)d_in[5],
      (const float*)d_in[6],  (const float*)d_in[7],
      (const float*)d_in[8],  (const float*)d_in[9],
      (const float*)d_in[10],
      (float*)d_out);
}

// Round 4
// 2841.510 us; speedup vs baseline: 1.1307x; 1.1307x over previous
//
#include <hip/hip_runtime.h>

#define NT 512
#define DIN 7
#define CTC 16
#define HSTR 132      // f16 stride per sample in H buffers (128 + 4 pad)
#define NBATCH 2048

typedef _Float16 half4 __attribute__((ext_vector_type(4)));
typedef _Float16 half8 __attribute__((ext_vector_type(8)));
typedef float    f32x4 __attribute__((ext_vector_type(4)));

#define MFMA16(A, B, C) __builtin_amdgcn_mfma_f32_16x16x16f16((A), (B), (C), 0, 0, 0)

__device__ __forceinline__ float rcp_fast(float x) { return __builtin_amdgcn_rcpf(x); }
__device__ __forceinline__ float sigm(float x)     { return rcp_fast(1.0f + __expf(-x)); }
__device__ __forceinline__ float tanh_fast(float v) {
  return fmaf(-2.0f, rcp_fast(1.0f + __expf(2.0f * v)), 1.0f);  // inf-safe both ends
}

// 4 waves / block, 16 samples / block, 128 blocks. Wave w owns h-indices
// [16w,16w+16): computes r-tile w, z-tile 4+w, n-tile 8+w via operand-swapped
// MFMA (D = W·h^T, bias in C). Gate pre-acts stay in the computing lane's
// registers; only new h (hi/lo f16) goes through LDS, double-buffered by step
// parity -> exactly ONE __syncthreads per step.
__global__ __launch_bounds__(256, 1) void gru4(
    const float* __restrict__ x,     // [B][T][7]
    const float* __restrict__ Wih0,  // [192][7]
    const float* __restrict__ Whh0,  // [192][64]
    const float* __restrict__ bih0,  // [192]
    const float* __restrict__ bhh0,  // [192]
    const float* __restrict__ Wih1,  // [192][64]
    const float* __restrict__ Whh1,  // [192][64]
    const float* __restrict__ bih1,  // [192]
    const float* __restrict__ bhh1,  // [192]
    const float* __restrict__ fcW,   // [64]
    const float* __restrict__ fcb,   // [1]
    float* __restrict__ out)         // [2048]
{
  __shared__ __align__(16) _Float16 H0[2][16][HSTR];  // [parity][sample][hi 64 | lo 64 | pad]
  __shared__ __align__(16) _Float16 H1[2][16][HSTR];
  __shared__ __align__(16) _Float16 xb[16][17][8];    // [sample][t(16)+pad][7 f16 + 0]
  __shared__ __align__(16) float bias[2][4][64];      // [layer][r,z,xn,hn][h-index]

  const int tid = threadIdx.x;
  const int col = tid & 15;        // sample within group / fragment col
  const int q   = (tid >> 4) & 3;  // k-quad / D-row quad
  const int w   = tid >> 6;        // wave id = owned h-tile
  const int s0  = blockIdx.x * 16;

  for (int i = tid; i < 2 * 16 * HSTR; i += 256) {
    ((_Float16*)H0)[i] = (_Float16)0; ((_Float16*)H1)[i] = (_Float16)0;
  }
  if (tid < 64) {
    const int g = tid;
    bias[0][0][g] = bih0[g]       + bhh0[g];
    bias[0][1][g] = bih0[64 + g]  + bhh0[64 + g];
    bias[0][2][g] = bih0[128 + g];
    bias[0][3][g] = bhh0[128 + g];
    bias[1][0][g] = bih1[g]       + bhh1[g];
    bias[1][1][g] = bih1[64 + g]  + bhh1[64 + g];
    bias[1][2][g] = bih1[128 + g];
    bias[1][3][g] = bhh1[128 + g];
  }

  // ---- weight A-fragments (lane holds W[16*tile+col][k=16kt+4q+i]) ----
  const int gr = w * 16 + col, gz = (4 + w) * 16 + col, gn = (8 + w) * 16 + col;
  half4 Wxr = (half4){}, Wxz = (half4){}, Wxn = (half4){};
#pragma unroll
  for (int i = 0; i < 4; ++i) {
    const int k = 4 * q + i;
    if (k < DIN) {
      Wxr[i] = (_Float16)Wih0[gr * DIN + k];
      Wxz[i] = (_Float16)Wih0[gz * DIN + k];
      Wxn[i] = (_Float16)Wih0[gn * DIN + k];
    }
  }
  half4 Ar[4], Az[4], An[4];   // Whh0
  half4 Pr[4], Pz[4], Pn[4];   // Wih1
  half4 Qr[4], Qz[4], Qn[4];   // Whh1
#pragma unroll
  for (int kt = 0; kt < 4; ++kt) {
    const int o = kt * 16 + 4 * q;
    f32x4 v;
    half4 h;
#define CVT(dst, W, g) v = *(const f32x4*)&W[(g) * 64 + o]; \
    h[0]=(_Float16)v[0]; h[1]=(_Float16)v[1]; h[2]=(_Float16)v[2]; h[3]=(_Float16)v[3]; dst[kt] = h;
    CVT(Ar, Whh0, gr) CVT(Az, Whh0, gz) CVT(An, Whh0, gn)
    CVT(Pr, Wih1, gr) CVT(Pz, Wih1, gz) CVT(Pn, Wih1, gn)
    CVT(Qr, Whh1, gr) CVT(Qz, Whh1, gz) CVT(Qn, Whh1, gn)
#undef CVT
  }
  __syncthreads();

  for (int tc = 0; tc < NT / CTC; ++tc) {
    // ---- stage 16-step x chunk (256 threads = 16 samples x 16 steps) ----
    {
      const int ss = tid >> 4, tt = tid & 15;
      const float* xp = x + ((size_t)(s0 + ss) * NT + tc * CTC + tt) * DIN;
      half8 v = (half8){};
#pragma unroll
      for (int d = 0; d < DIN; ++d) v[d] = (_Float16)xp[d];
      *(half8*)&xb[ss][tt][0] = v;
    }
    __syncthreads();

    for (int ti = 0; ti < CTC; ++ti) {
      const int p = ti & 1;  // read parity (tc*CTC even)

      // ================= layer 0 =================
      half4 xf = (half4){};
      if (q < 2) xf = *(const half4*)&xb[col][ti][4 * q];
      f32x4 ar  = MFMA16(Wxr, xf, *(const f32x4*)&bias[0][0][w * 16 + 4 * q]);
      f32x4 az  = MFMA16(Wxz, xf, *(const f32x4*)&bias[0][1][w * 16 + 4 * q]);
      f32x4 axn = MFMA16(Wxn, xf, *(const f32x4*)&bias[0][2][w * 16 + 4 * q]);
      f32x4 ahn = *(const f32x4*)&bias[0][3][w * 16 + 4 * q];

      half4 hf[8];
#pragma unroll
      for (int kt = 0; kt < 4; ++kt) {
        hf[kt]     = *(const half4*)&H0[p][col][16 * kt + 4 * q];
        hf[4 + kt] = *(const half4*)&H0[p][col][64 + 16 * kt + 4 * q];
      }
      f32x4 ar2 = (f32x4){}, az2 = (f32x4){}, ahn2 = (f32x4){};
#pragma unroll
      for (int kt = 0; kt < 4; ++kt) {
        ar   = MFMA16(Ar[kt], hf[kt],     ar);
        az   = MFMA16(Az[kt], hf[kt],     az);
        ahn  = MFMA16(An[kt], hf[kt],     ahn);
        ar2  = MFMA16(Ar[kt], hf[4 + kt], ar2);
        az2  = MFMA16(Az[kt], hf[4 + kt], az2);
        ahn2 = MFMA16(An[kt], hf[4 + kt], ahn2);
      }
      ar += ar2; az += az2; ahn += ahn2;

      half4 nhi, nlo;
#pragma unroll
      for (int i = 0; i < 4; ++i) {
        const float r = sigm(ar[i]);
        const float z = sigm(az[i]);
        const float n = tanh_fast(fmaf(r, ahn[i], axn[i]));
        const float hp = (float)hf[w][i] + (float)hf[4 + w][i];
        const float h  = fmaf(z, hp - n, n);
        const _Float16 hi = (_Float16)h;
        nhi[i] = hi; nlo[i] = (_Float16)(h - (float)hi);
      }
      *(half4*)&H0[p ^ 1][col][16 * w + 4 * q]      = nhi;
      *(half4*)&H0[p ^ 1][col][64 + 16 * w + 4 * q] = nlo;
      __syncthreads();   // the ONLY barrier per step

      // ================= layer 1 =================
      half4 g0[8], g1[8];
#pragma unroll
      for (int kt = 0; kt < 4; ++kt) {
        g0[kt]     = *(const half4*)&H0[p ^ 1][col][16 * kt + 4 * q];
        g0[4 + kt] = *(const half4*)&H0[p ^ 1][col][64 + 16 * kt + 4 * q];
        g1[kt]     = *(const half4*)&H1[p][col][16 * kt + 4 * q];
        g1[4 + kt] = *(const half4*)&H1[p][col][64 + 16 * kt + 4 * q];
      }
      ar  = *(const f32x4*)&bias[1][0][w * 16 + 4 * q];
      az  = *(const f32x4*)&bias[1][1][w * 16 + 4 * q];
      axn = *(const f32x4*)&bias[1][2][w * 16 + 4 * q];
      ahn = *(const f32x4*)&bias[1][3][w * 16 + 4 * q];
      ar2 = (f32x4){}; az2 = (f32x4){}; ahn2 = (f32x4){};
      f32x4 axn2 = (f32x4){};
#pragma unroll
      for (int kt = 0; kt < 4; ++kt) {   // ih1 · h0_new
        ar   = MFMA16(Pr[kt], g0[kt],     ar);
        az   = MFMA16(Pz[kt], g0[kt],     az);
        axn  = MFMA16(Pn[kt], g0[kt],     axn);
        ar2  = MFMA16(Pr[kt], g0[4 + kt], ar2);
        az2  = MFMA16(Pz[kt], g0[4 + kt], az2);
        axn2 = MFMA16(Pn[kt], g0[4 + kt], axn2);
      }
#pragma unroll
      for (int kt = 0; kt < 4; ++kt) {   // hh1 · h1_prev
        ar   = MFMA16(Qr[kt], g1[kt],     ar);
        az   = MFMA16(Qz[kt], g1[kt],     az);
        ahn  = MFMA16(Qn[kt], g1[kt],     ahn);
        ar2  = MFMA16(Qr[kt], g1[4 + kt], ar2);
        az2  = MFMA16(Qz[kt], g1[4 + kt], az2);
        ahn2 = MFMA16(Qn[kt], g1[4 + kt], ahn2);
      }
      ar += ar2; az += az2; axn += axn2; ahn += ahn2;
#pragma unroll
      for (int i = 0; i < 4; ++i) {
        const float r = sigm(ar[i]);
        const float z = sigm(az[i]);
        const float n = tanh_fast(fmaf(r, ahn[i], axn[i]));
        const float hp = (float)g1[w][i] + (float)g1[4 + w][i];
        const float h  = fmaf(z, hp - n, n);
        const _Float16 hi = (_Float16)h;
        nhi[i] = hi; nlo[i] = (_Float16)(h - (float)hi);
      }
      *(half4*)&H1[p ^ 1][col][16 * w + 4 * q]      = nhi;
      *(half4*)&H1[p ^ 1][col][64 + 16 * w + 4 * q] = nlo;
      // no barrier: next step's single barrier covers all hazards
    }
  }

  __syncthreads();
  // final h1 lives in parity 0 (t=511 writes H1[(511+1)&1]=H1[0])
  if (tid < 16) {
    float s = fcb[0];
    for (int j = 0; j < 64; ++j)
      s += ((float)H1[0][tid][j] + (float)H1[0][tid][64 + j]) * fcW[j];
    out[s0 + tid] = s;
  }
}

extern "C" void kernel_launch(void* const* d_in, const int* in_sizes, int n_in,
                              void* d_out, int out_size, void* d_ws, size_t ws_size,
                              hipStream_t stream) {
  (void)in_sizes; (void)n_in; (void)d_ws; (void)ws_size; (void)out_size;
  gru4<<<NBATCH / 16, 256, 0, stream>>>(
      (const float*)d_in[0],  (const float*)d_in[1],
      (const float*)d_in[2],  (const float*)d_in[3],
      (const float*)d_in[4],  (const float*)d_in[5],
      (const float*)d_in[6],  (const float*)d_in[7],
      (const float*)d_in[8],  (const float*)d_in[9],
      (const float*)d_in[10],
      (float*)d_out);
}

// Round 5
// 729.664 us; speedup vs baseline: 4.4033x; 3.8943x over previous
//
#include <hip/hip_runtime.h>

#define NT 512
#define DIN 7
#define CTC 16
#define HSTR 132      // f16 stride per sample in H buffers (128 + 4 pad)
#define NBATCH 2048

typedef _Float16 half4 __attribute__((ext_vector_type(4)));
typedef _Float16 half8 __attribute__((ext_vector_type(8)));
typedef float    f32x4 __attribute__((ext_vector_type(4)));

#define MFMA16(A, B, C) __builtin_amdgcn_mfma_f32_16x16x16f16((A), (B), (C), 0, 0, 0)

__device__ __forceinline__ float rcp_fast(float x) { return __builtin_amdgcn_rcpf(x); }
__device__ __forceinline__ float sigm(float x)     { return rcp_fast(1.0f + __expf(-x)); }
__device__ __forceinline__ float tanh_fast(float v) {
  return fmaf(-2.0f, rcp_fast(1.0f + __expf(2.0f * v)), 1.0f);  // inf-safe both ends
}

// 4 waves / block, 16 samples / block, 128 blocks. Wave w owns h-indices
// [16w,16w+16): computes its r/z/n tiles via operand-swapped MFMA (D = W·h^T,
// bias in C). Gate pre-acts stay in the computing lane's registers; only new h
// (hi/lo f16) goes through LDS, double-buffered by step parity -> ONE
// __syncthreads per step. NO runtime-indexed register arrays (rule #20):
// h_prev for the lane's own fragment is re-read from LDS with w folded into
// the ADDRESS, not into a register-array index.
__global__ __launch_bounds__(256, 1) void gru4(
    const float* __restrict__ x,     // [B][T][7]
    const float* __restrict__ Wih0,  // [192][7]
    const float* __restrict__ Whh0,  // [192][64]
    const float* __restrict__ bih0,  // [192]
    const float* __restrict__ bhh0,  // [192]
    const float* __restrict__ Wih1,  // [192][64]
    const float* __restrict__ Whh1,  // [192][64]
    const float* __restrict__ bih1,  // [192]
    const float* __restrict__ bhh1,  // [192]
    const float* __restrict__ fcW,   // [64]
    const float* __restrict__ fcb,   // [1]
    float* __restrict__ out)         // [2048]
{
  __shared__ __align__(16) _Float16 H0[2][16][HSTR];  // [parity][sample][hi 64 | lo 64 | pad]
  __shared__ __align__(16) _Float16 H1[2][16][HSTR];
  __shared__ __align__(16) _Float16 xb[16][17][8];    // [sample][t(16)+pad][7 f16 + 0]
  __shared__ __align__(16) float bias[2][4][64];      // [layer][r,z,xn,hn][h-index]

  const int tid = threadIdx.x;
  const int col = tid & 15;        // sample within group / fragment col
  const int q   = (tid >> 4) & 3;  // k-quad / D-row quad
  const int w   = tid >> 6;        // wave id = owned h-tile
  const int s0  = blockIdx.x * 16;

  for (int i = tid; i < 2 * 16 * HSTR; i += 256) {
    ((_Float16*)H0)[i] = (_Float16)0; ((_Float16*)H1)[i] = (_Float16)0;
  }
  if (tid < 64) {
    const int g = tid;
    bias[0][0][g] = bih0[g]       + bhh0[g];
    bias[0][1][g] = bih0[64 + g]  + bhh0[64 + g];
    bias[0][2][g] = bih0[128 + g];
    bias[0][3][g] = bhh0[128 + g];
    bias[1][0][g] = bih1[g]       + bhh1[g];
    bias[1][1][g] = bih1[64 + g]  + bhh1[64 + g];
    bias[1][2][g] = bih1[128 + g];
    bias[1][3][g] = bhh1[128 + g];
  }

  // ---- weight A-fragments (lane holds W[16*tile+col][k=16kt+4q+i]) ----
  const int gr = w * 16 + col, gz = (4 + w) * 16 + col, gn = (8 + w) * 16 + col;
  half4 Wxr = (half4){}, Wxz = (half4){}, Wxn = (half4){};
#pragma unroll
  for (int i = 0; i < 4; ++i) {
    const int k = 4 * q + i;
    if (k < DIN) {
      Wxr[i] = (_Float16)Wih0[gr * DIN + k];
      Wxz[i] = (_Float16)Wih0[gz * DIN + k];
      Wxn[i] = (_Float16)Wih0[gn * DIN + k];
    }
  }
  half4 Ar[4], Az[4], An[4];   // Whh0
  half4 Pr[4], Pz[4], Pn[4];   // Wih1
  half4 Qr[4], Qz[4], Qn[4];   // Whh1
#pragma unroll
  for (int kt = 0; kt < 4; ++kt) {
    const int o = kt * 16 + 4 * q;
    f32x4 v;
    half4 h;
#define CVT(dst, W, g) v = *(const f32x4*)&W[(g) * 64 + o]; \
    h[0]=(_Float16)v[0]; h[1]=(_Float16)v[1]; h[2]=(_Float16)v[2]; h[3]=(_Float16)v[3]; dst[kt] = h;
    CVT(Ar, Whh0, gr) CVT(Az, Whh0, gz) CVT(An, Whh0, gn)
    CVT(Pr, Wih1, gr) CVT(Pz, Wih1, gz) CVT(Pn, Wih1, gn)
    CVT(Qr, Whh1, gr) CVT(Qz, Whh1, gz) CVT(Qn, Whh1, gn)
#undef CVT
  }
  __syncthreads();

  for (int tc = 0; tc < NT / CTC; ++tc) {
    // ---- stage 16-step x chunk (256 threads = 16 samples x 16 steps) ----
    {
      const int ss = tid >> 4, tt = tid & 15;
      const float* xp = x + ((size_t)(s0 + ss) * NT + tc * CTC + tt) * DIN;
      half8 v = (half8){};
#pragma unroll
      for (int d = 0; d < DIN; ++d) v[d] = (_Float16)xp[d];
      *(half8*)&xb[ss][tt][0] = v;
    }
    __syncthreads();

    for (int ti = 0; ti < CTC; ++ti) {
      const int p = ti & 1;  // read parity (tc*CTC even)

      // ================= layer 0 =================
      // Batch ALL LDS reads for this phase up front (latency overlaps chains).
      half4 hf0, hf1, hf2, hf3, hl0, hl1, hl2, hl3;   // B-fragments (static names)
      hf0 = *(const half4*)&H0[p][col][0  + 4 * q];
      hf1 = *(const half4*)&H0[p][col][16 + 4 * q];
      hf2 = *(const half4*)&H0[p][col][32 + 4 * q];
      hf3 = *(const half4*)&H0[p][col][48 + 4 * q];
      hl0 = *(const half4*)&H0[p][col][64 + 0  + 4 * q];
      hl1 = *(const half4*)&H0[p][col][64 + 16 + 4 * q];
      hl2 = *(const half4*)&H0[p][col][64 + 32 + 4 * q];
      hl3 = *(const half4*)&H0[p][col][64 + 48 + 4 * q];
      // lane's OWN h_prev fragment: address (not register array) indexed by w
      half4 own_hi = *(const half4*)&H0[p][col][16 * w + 4 * q];
      half4 own_lo = *(const half4*)&H0[p][col][64 + 16 * w + 4 * q];

      half4 xf = (half4){};
      if (q < 2) xf = *(const half4*)&xb[col][ti][4 * q];
      f32x4 ar  = MFMA16(Wxr, xf, *(const f32x4*)&bias[0][0][w * 16 + 4 * q]);
      f32x4 az  = MFMA16(Wxz, xf, *(const f32x4*)&bias[0][1][w * 16 + 4 * q]);
      f32x4 axn = MFMA16(Wxn, xf, *(const f32x4*)&bias[0][2][w * 16 + 4 * q]);
      f32x4 ahn = *(const f32x4*)&bias[0][3][w * 16 + 4 * q];

      f32x4 ar2 = (f32x4){}, az2 = (f32x4){}, ahn2 = (f32x4){};
      ar   = MFMA16(Ar[0], hf0, ar);   az   = MFMA16(Az[0], hf0, az);
      ahn  = MFMA16(An[0], hf0, ahn);
      ar2  = MFMA16(Ar[1], hf1, ar2);  az2  = MFMA16(Az[1], hf1, az2);
      ahn2 = MFMA16(An[1], hf1, ahn2);
      ar   = MFMA16(Ar[2], hf2, ar);   az   = MFMA16(Az[2], hf2, az);
      ahn  = MFMA16(An[2], hf2, ahn);
      ar2  = MFMA16(Ar[3], hf3, ar2);  az2  = MFMA16(Az[3], hf3, az2);
      ahn2 = MFMA16(An[3], hf3, ahn2);
      ar   = MFMA16(Ar[0], hl0, ar);   az   = MFMA16(Az[0], hl0, az);
      ahn  = MFMA16(An[0], hl0, ahn);
      ar2  = MFMA16(Ar[1], hl1, ar2);  az2  = MFMA16(Az[1], hl1, az2);
      ahn2 = MFMA16(An[1], hl1, ahn2);
      ar   = MFMA16(Ar[2], hl2, ar);   az   = MFMA16(Az[2], hl2, az);
      ahn  = MFMA16(An[2], hl2, ahn);
      ar2  = MFMA16(Ar[3], hl3, ar2);  az2  = MFMA16(Az[3], hl3, az2);
      ahn2 = MFMA16(An[3], hl3, ahn2);
      ar += ar2; az += az2; ahn += ahn2;

      half4 nhi, nlo;
#pragma unroll
      for (int i = 0; i < 4; ++i) {
        const float r = sigm(ar[i]);
        const float z = sigm(az[i]);
        const float n = tanh_fast(fmaf(r, ahn[i], axn[i]));
        const float hp = (float)own_hi[i] + (float)own_lo[i];
        const float h  = fmaf(z, hp - n, n);
        const _Float16 hi = (_Float16)h;
        nhi[i] = hi; nlo[i] = (_Float16)(h - (float)hi);
      }
      *(half4*)&H0[p ^ 1][col][16 * w + 4 * q]      = nhi;
      *(half4*)&H0[p ^ 1][col][64 + 16 * w + 4 * q] = nlo;
      __syncthreads();   // the ONLY barrier per step

      // ================= layer 1 =================
      half4 g0h0, g0h1, g0h2, g0h3, g0l0, g0l1, g0l2, g0l3;
      half4 g1h0, g1h1, g1h2, g1h3, g1l0, g1l1, g1l2, g1l3;
      g0h0 = *(const half4*)&H0[p ^ 1][col][0  + 4 * q];
      g0h1 = *(const half4*)&H0[p ^ 1][col][16 + 4 * q];
      g0h2 = *(const half4*)&H0[p ^ 1][col][32 + 4 * q];
      g0h3 = *(const half4*)&H0[p ^ 1][col][48 + 4 * q];
      g0l0 = *(const half4*)&H0[p ^ 1][col][64 + 0  + 4 * q];
      g0l1 = *(const half4*)&H0[p ^ 1][col][64 + 16 + 4 * q];
      g0l2 = *(const half4*)&H0[p ^ 1][col][64 + 32 + 4 * q];
      g0l3 = *(const half4*)&H0[p ^ 1][col][64 + 48 + 4 * q];
      g1h0 = *(const half4*)&H1[p][col][0  + 4 * q];
      g1h1 = *(const half4*)&H1[p][col][16 + 4 * q];
      g1h2 = *(const half4*)&H1[p][col][32 + 4 * q];
      g1h3 = *(const half4*)&H1[p][col][48 + 4 * q];
      g1l0 = *(const half4*)&H1[p][col][64 + 0  + 4 * q];
      g1l1 = *(const half4*)&H1[p][col][64 + 16 + 4 * q];
      g1l2 = *(const half4*)&H1[p][col][64 + 32 + 4 * q];
      g1l3 = *(const half4*)&H1[p][col][64 + 48 + 4 * q];
      half4 o1hi = *(const half4*)&H1[p][col][16 * w + 4 * q];
      half4 o1lo = *(const half4*)&H1[p][col][64 + 16 * w + 4 * q];

      f32x4 br  = *(const f32x4*)&bias[1][0][w * 16 + 4 * q];
      f32x4 bz  = *(const f32x4*)&bias[1][1][w * 16 + 4 * q];
      f32x4 bxn = *(const f32x4*)&bias[1][2][w * 16 + 4 * q];
      f32x4 bhn = *(const f32x4*)&bias[1][3][w * 16 + 4 * q];
      f32x4 br2 = (f32x4){}, bz2 = (f32x4){}, bxn2 = (f32x4){}, bhn2 = (f32x4){};
      // ih1 · h0_new (hi+lo)
      br   = MFMA16(Pr[0], g0h0, br);   bz   = MFMA16(Pz[0], g0h0, bz);
      bxn  = MFMA16(Pn[0], g0h0, bxn);
      br2  = MFMA16(Pr[1], g0h1, br2);  bz2  = MFMA16(Pz[1], g0h1, bz2);
      bxn2 = MFMA16(Pn[1], g0h1, bxn2);
      br   = MFMA16(Pr[2], g0h2, br);   bz   = MFMA16(Pz[2], g0h2, bz);
      bxn  = MFMA16(Pn[2], g0h2, bxn);
      br2  = MFMA16(Pr[3], g0h3, br2);  bz2  = MFMA16(Pz[3], g0h3, bz2);
      bxn2 = MFMA16(Pn[3], g0h3, bxn2);
      br   = MFMA16(Pr[0], g0l0, br);   bz   = MFMA16(Pz[0], g0l0, bz);
      bxn  = MFMA16(Pn[0], g0l0, bxn);
      br2  = MFMA16(Pr[1], g0l1, br2);  bz2  = MFMA16(Pz[1], g0l1, bz2);
      bxn2 = MFMA16(Pn[1], g0l1, bxn2);
      br   = MFMA16(Pr[2], g0l2, br);   bz   = MFMA16(Pz[2], g0l2, bz);
      bxn  = MFMA16(Pn[2], g0l2, bxn);
      br2  = MFMA16(Pr[3], g0l3, br2);  bz2  = MFMA16(Pz[3], g0l3, bz2);
      bxn2 = MFMA16(Pn[3], g0l3, bxn2);
      // hh1 · h1_prev (hi+lo)
      br   = MFMA16(Qr[0], g1h0, br);   bz   = MFMA16(Qz[0], g1h0, bz);
      bhn  = MFMA16(Qn[0], g1h0, bhn);
      br2  = MFMA16(Qr[1], g1h1, br2);  bz2  = MFMA16(Qz[1], g1h1, bz2);
      bhn2 = MFMA16(Qn[1], g1h1, bhn2);
      br   = MFMA16(Qr[2], g1h2, br);   bz   = MFMA16(Qz[2], g1h2, bz);
      bhn  = MFMA16(Qn[2], g1h2, bhn);
      br2  = MFMA16(Qr[3], g1h3, br2);  bz2  = MFMA16(Qz[3], g1h3, bz2);
      bhn2 = MFMA16(Qn[3], g1h3, bhn2);
      br   = MFMA16(Qr[0], g1l0, br);   bz   = MFMA16(Qz[0], g1l0, bz);
      bhn  = MFMA16(Qn[0], g1l0, bhn);
      br2  = MFMA16(Qr[1], g1l1, br2);  bz2  = MFMA16(Qz[1], g1l1, bz2);
      bhn2 = MFMA16(Qn[1], g1l1, bhn2);
      br   = MFMA16(Qr[2], g1l2, br);   bz   = MFMA16(Qz[2], g1l2, bz);
      bhn  = MFMA16(Qn[2], g1l2, bhn);
      br2  = MFMA16(Qr[3], g1l3, br2);  bz2  = MFMA16(Qz[3], g1l3, bz2);
      bhn2 = MFMA16(Qn[3], g1l3, bhn2);
      br += br2; bz += bz2; bxn += bxn2; bhn += bhn2;

#pragma unroll
      for (int i = 0; i < 4; ++i) {
        const float r = sigm(br[i]);
        const float z = sigm(bz[i]);
        const float n = tanh_fast(fmaf(r, bhn[i], bxn[i]));
        const float hp = (float)o1hi[i] + (float)o1lo[i];
        const float h  = fmaf(z, hp - n, n);
        const _Float16 hi = (_Float16)h;
        nhi[i] = hi; nlo[i] = (_Float16)(h - (float)hi);
      }
      *(half4*)&H1[p ^ 1][col][16 * w + 4 * q]      = nhi;
      *(half4*)&H1[p ^ 1][col][64 + 16 * w + 4 * q] = nlo;
      // no barrier: next step's single barrier covers all hazards
    }
  }

  __syncthreads();
  // final h1 lives in parity 0 (t=511 writes H1[(511+1)&1]=H1[0])
  if (tid < 16) {
    float s = fcb[0];
    for (int j = 0; j < 64; ++j)
      s += ((float)H1[0][tid][j] + (float)H1[0][tid][64 + j]) * fcW[j];
    out[s0 + tid] = s;
  }
}

extern "C" void kernel_launch(void* const* d_in, const int* in_sizes, int n_in,
                              void* d_out, int out_size, void* d_ws, size_t ws_size,
                              hipStream_t stream) {
  (void)in_sizes; (void)n_in; (void)d_ws; (void)ws_size; (void)out_size;
  gru4<<<NBATCH / 16, 256, 0, stream>>>(
      (const float*)d_in[0],  (const float*)d_in[1],
      (const float*)d_in[2],  (const float*)d_in[3],
      (const float*)d_in[4],  (const float*)d_in[5],
      (const float*)d_in[6],  (const float*)d_in[7],
      (const float*)d_in[8],  (const float*)d_in[9],
      (const float*)d_in[10],
      (float*)d_out);
}

// Round 7
// 612.578 us; speedup vs baseline: 5.2449x; 1.1911x over previous
//
#include <hip/hip_runtime.h>

#define NT 512
#define DIN 7
#define CTC 64
#define HSTR 132      // f16 stride per sample in H buffers (128 + 4 pad)
#define NBATCH 2048

typedef _Float16 half4 __attribute__((ext_vector_type(4)));
typedef _Float16 half8 __attribute__((ext_vector_type(8)));
typedef float    f32x4 __attribute__((ext_vector_type(4)));

#define MFMA16(A, B, C) __builtin_amdgcn_mfma_f32_16x16x16f16((A), (B), (C), 0, 0, 0)

__device__ __forceinline__ float rcp_fast(float x) { return __builtin_amdgcn_rcpf(x); }
__device__ __forceinline__ float sigm(float x)     { return rcp_fast(1.0f + __expf(-x)); }
__device__ __forceinline__ float tanh_fast(float v) {
  return fmaf(-2.0f, rcp_fast(1.0f + __expf(2.0f * v)), 1.0f);  // inf-safe both ends
}

// 8 waves / block, 16 samples / block, 128 blocks. Software pipeline across
// layers: waves 0-3 compute layer0(step k) while waves 4-7 compute
// layer1(step k-1) — the two are independent, so each SIMD co-schedules one
// L0 wave + one L1 wave and their stalls hide each other. Within a group,
// wave w owns gate tiles {w, 4+w, 8+w} (r/z/n for h-indices [16w,16w+16)).
// Operand-swapped MFMA (D = W·h^T, bias preloaded in registers as C). Only
// new h (hi/lo f16, ~fp32 precision) crosses waves via LDS, double-buffered
// by tick parity -> exactly ONE __syncthreads per tick. No runtime-indexed
// register arrays (rule #20): lane's own h_prev read from LDS with w folded
// into the ADDRESS.
__global__ __launch_bounds__(512, 1) void gru8(
    const float* __restrict__ x,     // [B][T][7]
    const float* __restrict__ Wih0,  // [192][7]
    const float* __restrict__ Whh0,  // [192][64]
    const float* __restrict__ bih0,  // [192]
    const float* __restrict__ bhh0,  // [192]
    const float* __restrict__ Wih1,  // [192][64]
    const float* __restrict__ Whh1,  // [192][64]
    const float* __restrict__ bih1,  // [192]
    const float* __restrict__ bhh1,  // [192]
    const float* __restrict__ fcW,   // [64]
    const float* __restrict__ fcb,   // [1]
    float* __restrict__ out)         // [2048]
{
  __shared__ __align__(16) _Float16 H0[2][16][HSTR];  // [parity][sample][hi 64 | lo 64 | pad]
  __shared__ __align__(16) _Float16 H1[2][16][HSTR];
  __shared__ __align__(16) _Float16 xb[16][CTC + 1][8]; // [sample][t + pad][7 f16 + 0]

  const int tid = threadIdx.x;
  const int col = tid & 15;        // sample / fragment col
  const int q   = (tid >> 4) & 3;  // k-quad / D-row quad
  const int wv  = tid >> 6;        // 0..7
  const bool isL0 = (wv < 4);
  const int w   = isL0 ? wv : (wv - 4);   // gate-tile group 0..3
  const int s0  = blockIdx.x * 16;

  for (int i = tid; i < 2 * 16 * HSTR; i += 512) {
    ((_Float16*)H0)[i] = (_Float16)0; ((_Float16*)H1)[i] = (_Float16)0;
  }

  const int gr = w * 16 + col, gz = (4 + w) * 16 + col, gn = (8 + w) * 16 + col;
  const int bo = w * 16 + 4 * q;   // this lane's D-row gate offset (within 64)

  // ---- biases in registers (C-operand of the first MFMA in each chain) ----
  f32x4 bR, bZ, bXN, bHN;
  {
    const float* bi = isL0 ? bih0 : bih1;
    const float* bh = isL0 ? bhh0 : bhh1;
    f32x4 t1 = *(const f32x4*)&bi[bo],       t2 = *(const f32x4*)&bh[bo];
    bR = t1 + t2;
    t1 = *(const f32x4*)&bi[64 + bo];        t2 = *(const f32x4*)&bh[64 + bo];
    bZ = t1 + t2;
    bXN = *(const f32x4*)&bi[128 + bo];
    bHN = *(const f32x4*)&bh[128 + bo];
  }

  // ---- weight A-fragments (lane holds W[16*tile+col][k=16kt+4q+i]) ----
  half4 Wa[3] = {};                 // L0 only: Wih0 (r,z,n), K=16 (7 real)
  half4 M1[3][4] = {};              // L0: Whh0   | L1: Wih1
  half4 M2[3][4] = {};              // L0: unused | L1: Whh1

#define LOADW(dst, W, g, o) do {                      \
    f32x4 _v = *(const f32x4*)&(W)[(g) * 64 + (o)];   \
    half4 _h;                                          \
    _h[0] = (_Float16)_v[0]; _h[1] = (_Float16)_v[1];  \
    _h[2] = (_Float16)_v[2]; _h[3] = (_Float16)_v[3];  \
    (dst) = _h;                                        \
  } while (0)

  if (isL0) {
#pragma unroll
    for (int i = 0; i < 4; ++i) {
      const int kk = 4 * q + i;
      if (kk < DIN) {
        Wa[0][i] = (_Float16)Wih0[gr * DIN + kk];
        Wa[1][i] = (_Float16)Wih0[gz * DIN + kk];
        Wa[2][i] = (_Float16)Wih0[gn * DIN + kk];
      }
    }
#pragma unroll
    for (int kt = 0; kt < 4; ++kt) {
      const int o = kt * 16 + 4 * q;
      LOADW(M1[0][kt], Whh0, gr, o);
      LOADW(M1[1][kt], Whh0, gz, o);
      LOADW(M1[2][kt], Whh0, gn, o);
    }
  } else {
#pragma unroll
    for (int kt = 0; kt < 4; ++kt) {
      const int o = kt * 16 + 4 * q;
      LOADW(M1[0][kt], Wih1, gr, o);
      LOADW(M1[1][kt], Wih1, gz, o);
      LOADW(M1[2][kt], Wih1, gn, o);
      LOADW(M2[0][kt], Whh1, gr, o);
      LOADW(M2[1][kt], Whh1, gz, o);
      LOADW(M2[2][kt], Whh1, gn, o);
    }
  }
#undef LOADW
  __syncthreads();

  // ticks k = 0..NT: L0 computes h0(k) (k<NT), L1 computes h1(k-1) (k>0).
  // h0(t) lives in H0[(t+1)&1]; h1(t) lives in H1[(t+1)&1].
  for (int k = 0; k <= NT; ++k) {
    const int p = k & 1;

    if ((k & (CTC - 1)) == 0 && k < NT) {
      // ---- stage CTC-step x chunk: 16 samples x CTC steps x 7 f32 -> f16 ----
      for (int e = tid; e < 16 * CTC; e += 512) {
        const int ss = e & 15, tt = e >> 4;
        const float* xp = x + ((size_t)(s0 + ss) * NT + k + tt) * DIN;
        half8 v = (half8){};
#pragma unroll
        for (int d = 0; d < DIN; ++d) v[d] = (_Float16)xp[d];
        *(half8*)&xb[ss][tt][0] = v;
      }
      __syncthreads();
    }

    if (isL0) {
      if (k < NT) {
        const int ti = k & (CTC - 1);
        half4 hfh0, hfh1, hfh2, hfh3, hfl0, hfl1, hfl2, hfl3;
        hfh0 = *(const half4*)&H0[p][col][0  + 4 * q];
        hfh1 = *(const half4*)&H0[p][col][16 + 4 * q];
        hfh2 = *(const half4*)&H0[p][col][32 + 4 * q];
        hfh3 = *(const half4*)&H0[p][col][48 + 4 * q];
        hfl0 = *(const half4*)&H0[p][col][64 + 0  + 4 * q];
        hfl1 = *(const half4*)&H0[p][col][64 + 16 + 4 * q];
        hfl2 = *(const half4*)&H0[p][col][64 + 32 + 4 * q];
        hfl3 = *(const half4*)&H0[p][col][64 + 48 + 4 * q];
        half4 ohi = *(const half4*)&H0[p][col][16 * w + 4 * q];
        half4 olo = *(const half4*)&H0[p][col][64 + 16 * w + 4 * q];
        half4 xf = (half4){};
        if (q < 2) xf = *(const half4*)&xb[col][ti][4 * q];

        f32x4 ar  = MFMA16(Wa[0], xf, bR);
        f32x4 az  = MFMA16(Wa[1], xf, bZ);
        f32x4 axn = MFMA16(Wa[2], xf, bXN);
        f32x4 ahn = bHN;
        f32x4 ar2 = (f32x4){}, az2 = (f32x4){}, ahn2 = (f32x4){};
        ar   = MFMA16(M1[0][0], hfh0, ar);   az   = MFMA16(M1[1][0], hfh0, az);
        ahn  = MFMA16(M1[2][0], hfh0, ahn);
        ar2  = MFMA16(M1[0][1], hfh1, ar2);  az2  = MFMA16(M1[1][1], hfh1, az2);
        ahn2 = MFMA16(M1[2][1], hfh1, ahn2);
        ar   = MFMA16(M1[0][2], hfh2, ar);   az   = MFMA16(M1[1][2], hfh2, az);
        ahn  = MFMA16(M1[2][2], hfh2, ahn);
        ar2  = MFMA16(M1[0][3], hfh3, ar2);  az2  = MFMA16(M1[1][3], hfh3, az2);
        ahn2 = MFMA16(M1[2][3], hfh3, ahn2);
        ar   = MFMA16(M1[0][0], hfl0, ar);   az   = MFMA16(M1[1][0], hfl0, az);
        ahn  = MFMA16(M1[2][0], hfl0, ahn);
        ar2  = MFMA16(M1[0][1], hfl1, ar2);  az2  = MFMA16(M1[1][1], hfl1, az2);
        ahn2 = MFMA16(M1[2][1], hfl1, ahn2);
        ar   = MFMA16(M1[0][2], hfl2, ar);   az   = MFMA16(M1[1][2], hfl2, az);
        ahn  = MFMA16(M1[2][2], hfl2, ahn);
        ar2  = MFMA16(M1[0][3], hfl3, ar2);  az2  = MFMA16(M1[1][3], hfl3, az2);
        ahn2 = MFMA16(M1[2][3], hfl3, ahn2);
        ar += ar2; az += az2; ahn += ahn2;

        half4 nhi, nlo;
#pragma unroll
        for (int i = 0; i < 4; ++i) {
          const float r = sigm(ar[i]);
          const float z = sigm(az[i]);
          const float n = tanh_fast(fmaf(r, ahn[i], axn[i]));
          const float hp = (float)ohi[i] + (float)olo[i];
          const float h  = fmaf(z, hp - n, n);
          const _Float16 hi = (_Float16)h;
          nhi[i] = hi; nlo[i] = (_Float16)(h - (float)hi);
        }
        *(half4*)&H0[p ^ 1][col][16 * w + 4 * q]      = nhi;
        *(half4*)&H0[p ^ 1][col][64 + 16 * w + 4 * q] = nlo;
      }
    } else {
      if (k > 0) {
        // layer1, step t = k-1: reads h0(k-1) from H0[p], h1(k-2) from H1[p^1]
        half4 g0h0, g0h1, g0h2, g0h3, g0l0, g0l1, g0l2, g0l3;
        half4 g1h0, g1h1, g1h2, g1h3, g1l0, g1l1, g1l2, g1l3;
        g0h0 = *(const half4*)&H0[p][col][0  + 4 * q];
        g0h1 = *(const half4*)&H0[p][col][16 + 4 * q];
        g0h2 = *(const half4*)&H0[p][col][32 + 4 * q];
        g0h3 = *(const half4*)&H0[p][col][48 + 4 * q];
        g0l0 = *(const half4*)&H0[p][col][64 + 0  + 4 * q];
        g0l1 = *(const half4*)&H0[p][col][64 + 16 + 4 * q];
        g0l2 = *(const half4*)&H0[p][col][64 + 32 + 4 * q];
        g0l3 = *(const half4*)&H0[p][col][64 + 48 + 4 * q];
        g1h0 = *(const half4*)&H1[p ^ 1][col][0  + 4 * q];
        g1h1 = *(const half4*)&H1[p ^ 1][col][16 + 4 * q];
        g1h2 = *(const half4*)&H1[p ^ 1][col][32 + 4 * q];
        g1h3 = *(const half4*)&H1[p ^ 1][col][48 + 4 * q];
        g1l0 = *(const half4*)&H1[p ^ 1][col][64 + 0  + 4 * q];
        g1l1 = *(const half4*)&H1[p ^ 1][col][64 + 16 + 4 * q];
        g1l2 = *(const half4*)&H1[p ^ 1][col][64 + 32 + 4 * q];
        g1l3 = *(const half4*)&H1[p ^ 1][col][64 + 48 + 4 * q];
        half4 ohi = *(const half4*)&H1[p ^ 1][col][16 * w + 4 * q];
        half4 olo = *(const half4*)&H1[p ^ 1][col][64 + 16 * w + 4 * q];

        f32x4 br = bR, bz = bZ, bxn = bXN, bhn = bHN;
        f32x4 br2 = (f32x4){}, bz2 = (f32x4){}, bxn2 = (f32x4){}, bhn2 = (f32x4){};
        br   = MFMA16(M1[0][0], g0h0, br);   bz   = MFMA16(M1[1][0], g0h0, bz);
        bxn  = MFMA16(M1[2][0], g0h0, bxn);
        br2  = MFMA16(M1[0][1], g0h1, br2);  bz2  = MFMA16(M1[1][1], g0h1, bz2);
        bxn2 = MFMA16(M1[2][1], g0h1, bxn2);
        br   = MFMA16(M1[0][2], g0h2, br);   bz   = MFMA16(M1[1][2], g0h2, bz);
        bxn  = MFMA16(M1[2][2], g0h2, bxn);
        br2  = MFMA16(M1[0][3], g0h3, br2);  bz2  = MFMA16(M1[1][3], g0h3, bz2);
        bxn2 = MFMA16(M1[2][3], g0h3, bxn2);
        br   = MFMA16(M1[0][0], g0l0, br);   bz   = MFMA16(M1[1][0], g0l0, bz);
        bxn  = MFMA16(M1[2][0], g0l0, bxn);
        br2  = MFMA16(M1[0][1], g0l1, br2);  bz2  = MFMA16(M1[1][1], g0l1, bz2);
        bxn2 = MFMA16(M1[2][1], g0l1, bxn2);
        br   = MFMA16(M1[0][2], g0l2, br);   bz   = MFMA16(M1[1][2], g0l2, bz);
        bxn  = MFMA16(M1[2][2], g0l2, bxn);
        br2  = MFMA16(M1[0][3], g0l3, br2);  bz2  = MFMA16(M1[1][3], g0l3, bz2);
        bxn2 = MFMA16(M1[2][3], g0l3, bxn2);
        br   = MFMA16(M2[0][0], g1h0, br);   bz   = MFMA16(M2[1][0], g1h0, bz);
        bhn  = MFMA16(M2[2][0], g1h0, bhn);
        br2  = MFMA16(M2[0][1], g1h1, br2);  bz2  = MFMA16(M2[1][1], g1h1, bz2);
        bhn2 = MFMA16(M2[2][1], g1h1, bhn2);
        br   = MFMA16(M2[0][2], g1h2, br);   bz   = MFMA16(M2[1][2], g1h2, bz);
        bhn  = MFMA16(M2[2][2], g1h2, bhn);
        br2  = MFMA16(M2[0][3], g1h3, br2);  bz2  = MFMA16(M2[1][3], g1h3, bz2);
        bhn2 = MFMA16(M2[2][3], g1h3, bhn2);
        br   = MFMA16(M2[0][0], g1l0, br);   bz   = MFMA16(M2[1][0], g1l0, bz);
        bhn  = MFMA16(M2[2][0], g1l0, bhn);
        br2  = MFMA16(M2[0][1], g1l1, br2);  bz2  = MFMA16(M2[1][1], g1l1, bz2);
        bhn2 = MFMA16(M2[2][1], g1l1, bhn2);
        br   = MFMA16(M2[0][2], g1l2, br);   bz   = MFMA16(M2[1][2], g1l2, bz);
        bhn  = MFMA16(M2[2][2], g1l2, bhn);
        br2  = MFMA16(M2[0][3], g1l3, br2);  bz2  = MFMA16(M2[1][3], g1l3, bz2);
        bhn2 = MFMA16(M2[2][3], g1l3, bhn2);
        br += br2; bz += bz2; bxn += bxn2; bhn += bhn2;

        half4 nhi, nlo;
#pragma unroll
        for (int i = 0; i < 4; ++i) {
          const float r = sigm(br[i]);
          const float z = sigm(bz[i]);
          const float n = tanh_fast(fmaf(r, bhn[i], bxn[i]));
          const float hp = (float)ohi[i] + (float)olo[i];
          const float h  = fmaf(z, hp - n, n);
          const _Float16 hi = (_Float16)h;
          nhi[i] = hi; nlo[i] = (_Float16)(h - (float)hi);
        }
        *(half4*)&H1[p][col][16 * w + 4 * q]      = nhi;
        *(half4*)&H1[p][col][64 + 16 * w + 4 * q] = nlo;
      }
    }
    __syncthreads();   // the ONLY per-tick barrier
  }

  // ======== epilogue: out[s] = fcW · h1[s](t=511) + fcb ========
  // h1(511) written at tick 512 into H1[512&1] = H1[0]
  if (tid < 16) {
    float s = fcb[0];
    for (int j = 0; j < 64; ++j)
      s += ((float)H1[0][tid][j] + (float)H1[0][tid][64 + j]) * fcW[j];
    out[s0 + tid] = s;
  }
}

extern "C" void kernel_launch(void* const* d_in, const int* in_sizes, int n_in,
                              void* d_out, int out_size, void* d_ws, size_t ws_size,
                              hipStream_t stream) {
  (void)in_sizes; (void)n_in; (void)d_ws; (void)ws_size; (void)out_size;
  gru8<<<NBATCH / 16, 512, 0, stream>>>(
      (const float*)d_in[0],  (const float*)d_in[1],
      (const float*)d_in[2],  (const float*)d_in[3],
      (const float*)d_in[4],  (const float*)d_in[5],
      (const float*)d_in[6],  (const float*)d_in[7],
      (const float*)d_in[8],  (const float*)d_in[9],
      (const float*)d_in[10],
      (float*)d_out);
}

// Round 8
// 502.564 us; speedup vs baseline: 6.3931x; 1.2189x over previous
//
#include <hip/hip_runtime.h>

#define NT 512
#define DIN 7
#define CTC 64
#define HSTR 136      // f16 stride per sample in H buffers: 272B = 17*16 -> b128-aligned rows
#define NBATCH 2048

typedef _Float16 half4 __attribute__((ext_vector_type(4)));
typedef _Float16 half8 __attribute__((ext_vector_type(8)));
typedef float    f32x4 __attribute__((ext_vector_type(4)));

#define MFMA32(A, B, C) __builtin_amdgcn_mfma_f32_16x16x32_f16((A), (B), (C), 0, 0, 0)

__device__ __forceinline__ float rcp_fast(float x) { return __builtin_amdgcn_rcpf(x); }
__device__ __forceinline__ float sigm(float x)     { return rcp_fast(1.0f + __expf(-x)); }
__device__ __forceinline__ float tanh_fast(float v) {
  return fmaf(-2.0f, rcp_fast(1.0f + __expf(2.0f * v)), 1.0f);  // inf-safe both ends
}

// 8 waves / block, 16 samples / block, 128 blocks. Waves 0-3: layer0(step k);
// waves 4-7: layer1(step k-1) — independent, co-scheduled per SIMD. Native
// CDNA4 mfma_f32_16x16x32_f16 (K=32/instr): hi/lo K=128 matmul = 4 MFMA,
// 39 MFMA per SIMD per tick (was 75 with 16x16x16). Operand-swapped MFMA
// (D = W·h^T, bias in C); h as f16 hi+lo pair (~fp32). ONE barrier per tick.
// A-frag: W[g=16t+col][k=32kt+8q+i]; B-frag: h[k=32kt+8q+i] of sample col;
// D: row 4q+i (gate), col (sample) — verified family layout.
__global__ __launch_bounds__(512, 1) void gru8(
    const float* __restrict__ x,     // [B][T][7]
    const float* __restrict__ Wih0,  // [192][7]
    const float* __restrict__ Whh0,  // [192][64]
    const float* __restrict__ bih0,  // [192]
    const float* __restrict__ bhh0,  // [192]
    const float* __restrict__ Wih1,  // [192][64]
    const float* __restrict__ Whh1,  // [192][64]
    const float* __restrict__ bih1,  // [192]
    const float* __restrict__ bhh1,  // [192]
    const float* __restrict__ fcW,   // [64]
    const float* __restrict__ fcb,   // [1]
    float* __restrict__ out)         // [2048]
{
  __shared__ __align__(16) _Float16 H0[2][16][HSTR];  // [parity][sample][hi 64 | lo 64 | pad]
  __shared__ __align__(16) _Float16 H1[2][16][HSTR];
  __shared__ __align__(16) _Float16 xb[16][CTC + 1][8]; // [sample][t + pad][7 f16 + 0]

  const int tid = threadIdx.x;
  const int col = tid & 15;        // sample / fragment col
  const int q   = (tid >> 4) & 3;  // k-octet / D-row quad
  const int wv  = tid >> 6;        // 0..7
  const bool isL0 = (wv < 4);
  const int w   = isL0 ? wv : (wv - 4);   // gate-tile group 0..3
  const int s0  = blockIdx.x * 16;

  for (int i = tid; i < 2 * 16 * HSTR; i += 512) {
    ((_Float16*)H0)[i] = (_Float16)0; ((_Float16*)H1)[i] = (_Float16)0;
  }

  const int gr = w * 16 + col, gz = (4 + w) * 16 + col, gn = (8 + w) * 16 + col;
  const int bo = w * 16 + 4 * q;   // this lane's D-row gate offset (within 64)

  // ---- biases in registers (C-operand of the first MFMA in each chain) ----
  f32x4 bR, bZ, bXN, bHN;
  {
    const float* bi = isL0 ? bih0 : bih1;
    const float* bh = isL0 ? bhh0 : bhh1;
    f32x4 t1 = *(const f32x4*)&bi[bo],       t2 = *(const f32x4*)&bh[bo];
    bR = t1 + t2;
    t1 = *(const f32x4*)&bi[64 + bo];        t2 = *(const f32x4*)&bh[64 + bo];
    bZ = t1 + t2;
    bXN = *(const f32x4*)&bi[128 + bo];
    bHN = *(const f32x4*)&bh[128 + bo];
  }

  // ---- weight A-fragments: lane holds W[g][k = 32*kt + 8*q + i], i=0..7 ----
  half8 Wa0 = {}, Wa1 = {}, Wa2 = {};           // L0: Wih0 r/z/n (q==0 lanes only)
  half8 A0k0, A0k1, A1k0, A1k1, A2k0, A2k1;     // L0: Whh0 | L1: Wih1
  half8 B0k0 = {}, B0k1 = {}, B1k0 = {}, B1k1 = {}, B2k0 = {}, B2k1 = {}; // L1: Whh1

#define LDW8(dst, W, g, kt) do {                                   \
    f32x4 _a = *(const f32x4*)&(W)[(g) * 64 + 32 * (kt) + 8 * q];  \
    f32x4 _b = *(const f32x4*)&(W)[(g) * 64 + 32 * (kt) + 8 * q + 4]; \
    half8 _h;                                                       \
    _h[0] = (_Float16)_a[0]; _h[1] = (_Float16)_a[1];               \
    _h[2] = (_Float16)_a[2]; _h[3] = (_Float16)_a[3];               \
    _h[4] = (_Float16)_b[0]; _h[5] = (_Float16)_b[1];               \
    _h[6] = (_Float16)_b[2]; _h[7] = (_Float16)_b[3];               \
    (dst) = _h;                                                     \
  } while (0)

  if (isL0) {
    if (q == 0) {
#pragma unroll
      for (int i = 0; i < DIN; ++i) {
        Wa0[i] = (_Float16)Wih0[gr * DIN + i];
        Wa1[i] = (_Float16)Wih0[gz * DIN + i];
        Wa2[i] = (_Float16)Wih0[gn * DIN + i];
      }
    }
    LDW8(A0k0, Whh0, gr, 0); LDW8(A0k1, Whh0, gr, 1);
    LDW8(A1k0, Whh0, gz, 0); LDW8(A1k1, Whh0, gz, 1);
    LDW8(A2k0, Whh0, gn, 0); LDW8(A2k1, Whh0, gn, 1);
  } else {
    LDW8(A0k0, Wih1, gr, 0); LDW8(A0k1, Wih1, gr, 1);
    LDW8(A1k0, Wih1, gz, 0); LDW8(A1k1, Wih1, gz, 1);
    LDW8(A2k0, Wih1, gn, 0); LDW8(A2k1, Wih1, gn, 1);
    LDW8(B0k0, Whh1, gr, 0); LDW8(B0k1, Whh1, gr, 1);
    LDW8(B1k0, Whh1, gz, 0); LDW8(B1k1, Whh1, gz, 1);
    LDW8(B2k0, Whh1, gn, 0); LDW8(B2k1, Whh1, gn, 1);
  }
#undef LDW8
  __syncthreads();

  // ticks k = 0..NT: L0 computes h0(k) (k<NT), L1 computes h1(k-1) (k>0).
  // h0(t) lives in H0[(t+1)&1]; h1(t) lives in H1[(t+1)&1].
  for (int k = 0; k <= NT; ++k) {
    const int p = k & 1;

    if ((k & (CTC - 1)) == 0 && k < NT) {
      // ---- stage CTC-step x chunk: 16 samples x CTC steps x 7 f32 -> f16 ----
      for (int e = tid; e < 16 * CTC; e += 512) {
        const int ss = e & 15, tt = e >> 4;
        const float* xp = x + ((size_t)(s0 + ss) * NT + k + tt) * DIN;
        half8 v = (half8){};
#pragma unroll
        for (int d = 0; d < DIN; ++d) v[d] = (_Float16)xp[d];
        *(half8*)&xb[ss][tt][0] = v;
      }
      __syncthreads();
    }

    if (isL0) {
      if (k < NT) {
        const int ti = k & (CTC - 1);
        // B-fragments of h0(k-1): hi/lo, kt=0,1 (k = 32*kt + 8*q + i)
        half8 hh0 = *(const half8*)&H0[p][col][ 0 + 8 * q];
        half8 hh1 = *(const half8*)&H0[p][col][32 + 8 * q];
        half8 hl0 = *(const half8*)&H0[p][col][64 + 8 * q];
        half8 hl1 = *(const half8*)&H0[p][col][96 + 8 * q];
        half4 ohi = *(const half4*)&H0[p][col][16 * w + 4 * q];
        half4 olo = *(const half4*)&H0[p][col][64 + 16 * w + 4 * q];
        half8 xf = (half8){};
        if (q == 0) xf = *(const half8*)&xb[col][ti][0];

        f32x4 ar = MFMA32(Wa0, xf, bR);
        ar = MFMA32(A0k0, hh0, ar);
        ar = MFMA32(A0k1, hh1, ar);
        f32x4 ar2 = MFMA32(A0k0, hl0, (f32x4){});
        ar2 = MFMA32(A0k1, hl1, ar2);

        f32x4 az = MFMA32(Wa1, xf, bZ);
        az = MFMA32(A1k0, hh0, az);
        az = MFMA32(A1k1, hh1, az);
        f32x4 az2 = MFMA32(A1k0, hl0, (f32x4){});
        az2 = MFMA32(A1k1, hl1, az2);

        f32x4 axn = MFMA32(Wa2, xf, bXN);
        f32x4 ahn = MFMA32(A2k0, hh0, bHN);
        ahn = MFMA32(A2k1, hh1, ahn);
        f32x4 ahn2 = MFMA32(A2k0, hl0, (f32x4){});
        ahn2 = MFMA32(A2k1, hl1, ahn2);

        ar += ar2; az += az2; ahn += ahn2;

        half4 nhi, nlo;
#pragma unroll
        for (int i = 0; i < 4; ++i) {
          const float r = sigm(ar[i]);
          const float z = sigm(az[i]);
          const float n = tanh_fast(fmaf(r, ahn[i], axn[i]));
          const float hp = (float)ohi[i] + (float)olo[i];
          const float h  = fmaf(z, hp - n, n);
          const _Float16 hi = (_Float16)h;
          nhi[i] = hi; nlo[i] = (_Float16)(h - (float)hi);
        }
        *(half4*)&H0[p ^ 1][col][16 * w + 4 * q]      = nhi;
        *(half4*)&H0[p ^ 1][col][64 + 16 * w + 4 * q] = nlo;
      }
    } else {
      if (k > 0) {
        // layer1, step t = k-1: h0(k-1) in H0[p], h1(k-2) in H1[p^1]
        half8 g0h0 = *(const half8*)&H0[p][col][ 0 + 8 * q];
        half8 g0h1 = *(const half8*)&H0[p][col][32 + 8 * q];
        half8 g0l0 = *(const half8*)&H0[p][col][64 + 8 * q];
        half8 g0l1 = *(const half8*)&H0[p][col][96 + 8 * q];
        half8 g1h0 = *(const half8*)&H1[p ^ 1][col][ 0 + 8 * q];
        half8 g1h1 = *(const half8*)&H1[p ^ 1][col][32 + 8 * q];
        half8 g1l0 = *(const half8*)&H1[p ^ 1][col][64 + 8 * q];
        half8 g1l1 = *(const half8*)&H1[p ^ 1][col][96 + 8 * q];
        half4 ohi  = *(const half4*)&H1[p ^ 1][col][16 * w + 4 * q];
        half4 olo  = *(const half4*)&H1[p ^ 1][col][64 + 16 * w + 4 * q];

        f32x4 br = MFMA32(A0k0, g0h0, bR);
        br = MFMA32(A0k1, g0h1, br);
        br = MFMA32(B0k0, g1h0, br);
        br = MFMA32(B0k1, g1h1, br);
        f32x4 br2 = MFMA32(A0k0, g0l0, (f32x4){});
        br2 = MFMA32(A0k1, g0l1, br2);
        br2 = MFMA32(B0k0, g1l0, br2);
        br2 = MFMA32(B0k1, g1l1, br2);

        f32x4 bz = MFMA32(A1k0, g0h0, bZ);
        bz = MFMA32(A1k1, g0h1, bz);
        bz = MFMA32(B1k0, g1h0, bz);
        bz = MFMA32(B1k1, g1h1, bz);
        f32x4 bz2 = MFMA32(A1k0, g0l0, (f32x4){});
        bz2 = MFMA32(A1k1, g0l1, bz2);
        bz2 = MFMA32(B1k0, g1l0, bz2);
        bz2 = MFMA32(B1k1, g1l1, bz2);

        f32x4 bxn = MFMA32(A2k0, g0h0, bXN);
        bxn = MFMA32(A2k1, g0h1, bxn);
        f32x4 bxn2 = MFMA32(A2k0, g0l0, (f32x4){});
        bxn2 = MFMA32(A2k1, g0l1, bxn2);

        f32x4 bhn = MFMA32(B2k0, g1h0, bHN);
        bhn = MFMA32(B2k1, g1h1, bhn);
        f32x4 bhn2 = MFMA32(B2k0, g1l0, (f32x4){});
        bhn2 = MFMA32(B2k1, g1l1, bhn2);

        br += br2; bz += bz2; bxn += bxn2; bhn += bhn2;

        half4 nhi, nlo;
#pragma unroll
        for (int i = 0; i < 4; ++i) {
          const float r = sigm(br[i]);
          const float z = sigm(bz[i]);
          const float n = tanh_fast(fmaf(r, bhn[i], bxn[i]));
          const float hp = (float)ohi[i] + (float)olo[i];
          const float h  = fmaf(z, hp - n, n);
          const _Float16 hi = (_Float16)h;
          nhi[i] = hi; nlo[i] = (_Float16)(h - (float)hi);
        }
        *(half4*)&H1[p][col][16 * w + 4 * q]      = nhi;
        *(half4*)&H1[p][col][64 + 16 * w + 4 * q] = nlo;
      }
    }
    __syncthreads();   // the ONLY per-tick barrier
  }

  // ======== epilogue: out[s] = fcW · h1[s](t=511) + fcb ========
  // h1(511) written at tick 512 (p=0) into H1[0]
  if (tid < 16) {
    float s = fcb[0];
    for (int j = 0; j < 64; ++j)
      s += ((float)H1[0][tid][j] + (float)H1[0][tid][64 + j]) * fcW[j];
    out[s0 + tid] = s;
  }
}

extern "C" void kernel_launch(void* const* d_in, const int* in_sizes, int n_in,
                              void* d_out, int out_size, void* d_ws, size_t ws_size,
                              hipStream_t stream) {
  (void)in_sizes; (void)n_in; (void)d_ws; (void)ws_size; (void)out_size;
  gru8<<<NBATCH / 16, 512, 0, stream>>>(
      (const float*)d_in[0],  (const float*)d_in[1],
      (const float*)d_in[2],  (const float*)d_in[3],
      (const float*)d_in[4],  (const float*)d_in[5],
      (const float*)d_in[6],  (const float*)d_in[7],
      (const float*)d_in[8],  (const float*)d_in[9],
      (const float*)d_in[10],
      (float*)d_out);
}

// Round 9
// 349.937 us; speedup vs baseline: 9.1814x; 1.4362x over previous
//
#include <hip/hip_runtime.h>

#define NT 512
#define DIN 7
#define CTC 64
#define HSTR 72       // f16 stride per sample row: 64 data + 8 pad = 144 B
#define NBATCH 2048

typedef _Float16 half4 __attribute__((ext_vector_type(4)));
typedef _Float16 half8 __attribute__((ext_vector_type(8)));
typedef float    f32x4 __attribute__((ext_vector_type(4)));

#define MFMA32(A, B, C) __builtin_amdgcn_mfma_f32_16x16x32_f16((A), (B), (C), 0, 0, 0)

__device__ __forceinline__ float rcp_fast(float x) { return __builtin_amdgcn_rcpf(x); }
__device__ __forceinline__ float sigm(float x)     { return rcp_fast(1.0f + __expf(-x)); }
__device__ __forceinline__ float tanh_fast(float v) {
  return fmaf(-2.0f, rcp_fast(1.0f + __expf(2.0f * v)), 1.0f);  // inf-safe both ends
}

// 8 waves / block, 16 samples / block, 128 blocks. Waves 0-3: layer0(tick k);
// waves 4-7: layer1(tick k-1). Operand-swapped MFMA (D = W·h^T, bias in C).
// h is carried in fp32 REGISTERS by the owning lane (exact recurrence via
// z·h_prev); only the matmul operand is rounded to f16 and exchanged via LDS
// (single precision, no hi/lo pair): 84 MFMA + ~28 b128 LDS reads per block
// per tick (half of round 8). ONE barrier per tick.
__global__ __launch_bounds__(512, 1) void gru8(
    const float* __restrict__ x,     // [B][T][7]
    const float* __restrict__ Wih0,  // [192][7]
    const float* __restrict__ Whh0,  // [192][64]
    const float* __restrict__ bih0,  // [192]
    const float* __restrict__ bhh0,  // [192]
    const float* __restrict__ Wih1,  // [192][64]
    const float* __restrict__ Whh1,  // [192][64]
    const float* __restrict__ bih1,  // [192]
    const float* __restrict__ bhh1,  // [192]
    const float* __restrict__ fcW,   // [64]
    const float* __restrict__ fcb,   // [1]
    float* __restrict__ out)         // [2048]
{
  __shared__ __align__(16) _Float16 H0[2][16][HSTR];   // [parity][sample][64 f16 + pad]
  __shared__ __align__(16) _Float16 H1[2][16][HSTR];
  __shared__ __align__(16) _Float16 xb[16][CTC + 1][8]; // [sample][t + pad][7 f16 + 0]
  __shared__ float red[4][16];                          // epilogue partials

  const int tid = threadIdx.x;
  const int col = tid & 15;        // sample / fragment col
  const int q   = (tid >> 4) & 3;  // k-octet / D-row quad
  const int wv  = tid >> 6;        // 0..7
  const bool isL0 = (wv < 4);
  const int w   = isL0 ? wv : (wv - 4);   // gate-tile group 0..3
  const int s0  = blockIdx.x * 16;

  for (int i = tid; i < 2 * 16 * HSTR; i += 512) {
    ((_Float16*)H0)[i] = (_Float16)0; ((_Float16*)H1)[i] = (_Float16)0;
  }

  const int gr = w * 16 + col, gz = (4 + w) * 16 + col, gn = (8 + w) * 16 + col;
  const int bo = w * 16 + 4 * q;   // this lane's D-row gate offset (within 64)

  // ---- biases in registers (C-operand of the first MFMA in each chain) ----
  f32x4 bR, bZ, bXN, bHN;
  {
    const float* bi = isL0 ? bih0 : bih1;
    const float* bh = isL0 ? bhh0 : bhh1;
    f32x4 t1 = *(const f32x4*)&bi[bo],       t2 = *(const f32x4*)&bh[bo];
    bR = t1 + t2;
    t1 = *(const f32x4*)&bi[64 + bo];        t2 = *(const f32x4*)&bh[64 + bo];
    bZ = t1 + t2;
    bXN = *(const f32x4*)&bi[128 + bo];
    bHN = *(const f32x4*)&bh[128 + bo];
  }

  // ---- weight A-fragments: lane holds W[g][k = 32*kt + 8*q + i], i=0..7 ----
  half8 Wa0 = {}, Wa1 = {}, Wa2 = {};           // L0: Wih0 r/z/n (q==0 lanes only)
  half8 A0k0, A0k1, A1k0, A1k1, A2k0, A2k1;     // L0: Whh0 | L1: Wih1
  half8 B0k0 = {}, B0k1 = {}, B1k0 = {}, B1k1 = {}, B2k0 = {}, B2k1 = {}; // L1: Whh1

#define LDW8(dst, W, g, kt) do {                                   \
    f32x4 _a = *(const f32x4*)&(W)[(g) * 64 + 32 * (kt) + 8 * q];  \
    f32x4 _b = *(const f32x4*)&(W)[(g) * 64 + 32 * (kt) + 8 * q + 4]; \
    half8 _h;                                                       \
    _h[0] = (_Float16)_a[0]; _h[1] = (_Float16)_a[1];               \
    _h[2] = (_Float16)_a[2]; _h[3] = (_Float16)_a[3];               \
    _h[4] = (_Float16)_b[0]; _h[5] = (_Float16)_b[1];               \
    _h[6] = (_Float16)_b[2]; _h[7] = (_Float16)_b[3];               \
    (dst) = _h;                                                     \
  } while (0)

  if (isL0) {
    if (q == 0) {
#pragma unroll
      for (int i = 0; i < DIN; ++i) {
        Wa0[i] = (_Float16)Wih0[gr * DIN + i];
        Wa1[i] = (_Float16)Wih0[gz * DIN + i];
        Wa2[i] = (_Float16)Wih0[gn * DIN + i];
      }
    }
    LDW8(A0k0, Whh0, gr, 0); LDW8(A0k1, Whh0, gr, 1);
    LDW8(A1k0, Whh0, gz, 0); LDW8(A1k1, Whh0, gz, 1);
    LDW8(A2k0, Whh0, gn, 0); LDW8(A2k1, Whh0, gn, 1);
  } else {
    LDW8(A0k0, Wih1, gr, 0); LDW8(A0k1, Wih1, gr, 1);
    LDW8(A1k0, Wih1, gz, 0); LDW8(A1k1, Wih1, gz, 1);
    LDW8(A2k0, Wih1, gn, 0); LDW8(A2k1, Wih1, gn, 1);
    LDW8(B0k0, Whh1, gr, 0); LDW8(B0k1, Whh1, gr, 1);
    LDW8(B1k0, Whh1, gz, 0); LDW8(B1k1, Whh1, gz, 1);
    LDW8(B2k0, Whh1, gn, 0); LDW8(B2k1, Whh1, gn, 1);
  }
#undef LDW8
  __syncthreads();

  // lane's own h slice [16w+4q, +4), fp32, carried across ticks (exact)
  f32x4 hown = (f32x4){};

  // ticks k = 0..NT: L0 computes h0(k) (k<NT), L1 computes h1(k-1) (k>0).
  // h0(t) f16 copy lives in H0[(t+1)&1]; h1(t) in H1[(t+1)&1].
  for (int k = 0; k <= NT; ++k) {
    const int p = k & 1;

    if ((k & (CTC - 1)) == 0 && k < NT) {
      // ---- stage CTC-step x chunk: 16 samples x CTC steps x 7 f32 -> f16 ----
      for (int e = tid; e < 16 * CTC; e += 512) {
        const int ss = e & 15, tt = e >> 4;
        const float* xp = x + ((size_t)(s0 + ss) * NT + k + tt) * DIN;
        half8 v = (half8){};
#pragma unroll
        for (int d = 0; d < DIN; ++d) v[d] = (_Float16)xp[d];
        *(half8*)&xb[ss][tt][0] = v;
      }
      __syncthreads();
    }

    if (isL0) {
      if (k < NT) {
        const int ti = k & (CTC - 1);
        // B-fragments of h0(k-1) f16: k = 32*kt + 8*q + i
        half8 hh0 = *(const half8*)&H0[p][col][ 0 + 8 * q];
        half8 hh1 = *(const half8*)&H0[p][col][32 + 8 * q];
        half8 xf = (half8){};
        if (q == 0) xf = *(const half8*)&xb[col][ti][0];

        // two short chains per gate, then combine
        f32x4 ar  = MFMA32(A0k0, hh0, MFMA32(Wa0, xf, bR));
        f32x4 ar2 = MFMA32(A0k1, hh1, (f32x4){});
        f32x4 az  = MFMA32(A1k0, hh0, MFMA32(Wa1, xf, bZ));
        f32x4 az2 = MFMA32(A1k1, hh1, (f32x4){});
        f32x4 axn = MFMA32(Wa2, xf, bXN);
        f32x4 ahn = MFMA32(A2k0, hh0, bHN);
        f32x4 ahn2 = MFMA32(A2k1, hh1, (f32x4){});
        ar += ar2; az += az2; ahn += ahn2;

        half4 nh;
#pragma unroll
        for (int i = 0; i < 4; ++i) {
          const float r = sigm(ar[i]);
          const float z = sigm(az[i]);
          const float n = tanh_fast(fmaf(r, ahn[i], axn[i]));
          hown[i] = fmaf(z, hown[i] - n, n);     // exact fp32 recurrence
          nh[i] = (_Float16)hown[i];
        }
        *(half4*)&H0[p ^ 1][col][16 * w + 4 * q] = nh;
      }
    } else {
      if (k > 0) {
        // layer1, step t = k-1: h0(k-1) f16 in H0[p], h1(k-2) f16 in H1[p^1]
        half8 g0h0 = *(const half8*)&H0[p][col][ 0 + 8 * q];
        half8 g0h1 = *(const half8*)&H0[p][col][32 + 8 * q];
        half8 g1h0 = *(const half8*)&H1[p ^ 1][col][ 0 + 8 * q];
        half8 g1h1 = *(const half8*)&H1[p ^ 1][col][32 + 8 * q];

        f32x4 br  = MFMA32(A0k1, g0h1, MFMA32(A0k0, g0h0, bR));
        f32x4 br2 = MFMA32(B0k1, g1h1, MFMA32(B0k0, g1h0, (f32x4){}));
        f32x4 bz  = MFMA32(A1k1, g0h1, MFMA32(A1k0, g0h0, bZ));
        f32x4 bz2 = MFMA32(B1k1, g1h1, MFMA32(B1k0, g1h0, (f32x4){}));
        f32x4 bxn = MFMA32(A2k1, g0h1, MFMA32(A2k0, g0h0, bXN));
        f32x4 bhn = MFMA32(B2k1, g1h1, MFMA32(B2k0, g1h0, bHN));
        br += br2; bz += bz2;

        half4 nh;
#pragma unroll
        for (int i = 0; i < 4; ++i) {
          const float r = sigm(br[i]);
          const float z = sigm(bz[i]);
          const float n = tanh_fast(fmaf(r, bhn[i], bxn[i]));
          hown[i] = fmaf(z, hown[i] - n, n);     // exact fp32 recurrence
          nh[i] = (_Float16)hown[i];
        }
        *(half4*)&H1[p][col][16 * w + 4 * q] = nh;
      }
    }
    __syncthreads();   // the ONLY per-tick barrier
  }

  // ======== epilogue: out[s] = fcW · h1[s](t=511) + fcb ========
  // exact fp32 h1 lives in L1 waves' hown registers
  if (!isL0) {
    f32x4 fw = *(const f32x4*)&fcW[bo];
    float partial = hown[0] * fw[0] + hown[1] * fw[1] +
                    hown[2] * fw[2] + hown[3] * fw[3];
    partial += __shfl_xor(partial, 16, 64);
    partial += __shfl_xor(partial, 32, 64);      // all lanes: sum over q
    if ((tid & 63) < 16) red[w][col] = partial;
  }
  __syncthreads();
  if (tid < 16) {
    out[s0 + tid] = red[0][tid] + red[1][tid] + red[2][tid] + red[3][tid] + fcb[0];
  }
}

extern "C" void kernel_launch(void* const* d_in, const int* in_sizes, int n_in,
                              void* d_out, int out_size, void* d_ws, size_t ws_size,
                              hipStream_t stream) {
  (void)in_sizes; (void)n_in; (void)d_ws; (void)ws_size; (void)out_size;
  gru8<<<NBATCH / 16, 512, 0, stream>>>(
      (const float*)d_in[0],  (const float*)d_in[1],
      (const float*)d_in[2],  (const float*)d_in[3],
      (const float*)d_in[4],  (const float*)d_in[5],
      (const float*)d_in[6],  (const float*)d_in[7],
      (const float*)d_in[8],  (const float*)d_in[9],
      (const float*)d_in[10],
      (float*)d_out);
}